// Round 11
// baseline (62.336 us; speedup 1.0000x reference)
//
#include <hip/hip_runtime.h>
#include <math.h>

#define B 8
#define L 8192
#define H 1024
#define SCALE 0.03125f   // 1/sqrt(1024)

#define MAX_N 160        // >= 129 cantor keys
#define CPB   128        // colsum slices per batch
#define ROWSC (L / CPB)  // 64 rows per slice
#define NPART CPB        // partial rows per batch
#define NSLICE (CPB * B) // 1024 total colsum slices

// ws layout (float offsets) — total (2*B*H + NPART*B*H)*4 = 4.26 MB (safe).
//   OFF_OUTS: hil_out (B*H) then can_out (B*H)
//   OFF_PART: partials (NPART*B*H), layout [p][b][h]
#define OFF_OUTS 0
#define OFF_PART (2 * B * H)

__device__ inline void d2xy_dev(int n, int d, int* px, int* py) {
    int x = 0, y = 0;
    for (int s = 1; s < n; s *= 2) {
        int rx = 1 & (d / 2);
        int ry = 1 & (d ^ rx);
        if (ry == 0) {
            if (rx == 1) { x = s - 1 - x; y = s - 1 - y; }
            int t = x; x = y; y = t;
        }
        x += s * rx; y += s * ry;
        d /= 4;
    }
    *px = x; *py = y;
}

__device__ inline int xy2d_dev(int n, int x, int y) {
    int d = 0;
    for (int s = n / 2; s > 0; s /= 2) {
        int rx = ((x & s) > 0) ? 1 : 0;
        int ry = ((y & s) > 0) ? 1 : 0;
        d += s * s * ((3 * rx) ^ ry);
        if (ry == 0) {
            if (rx == 1) { x = s - 1 - x; y = s - 1 - y; }
            int t = x; x = y; y = t;
        }
    }
    return d;
}

// Colsum slice cb: batch b = cb>>7, phase kp = cb&127. Windowed row
// interleave (rows l = kp + m*128): a batch's 128 slices collectively
// sweep one contiguous 512KB window (8 linear streams machine-wide).
__device__ inline void colsum_slice(int cb, int tid,
                                    const float* __restrict__ v,
                                    float* __restrict__ ws_f) {
    int b  = cb >> 7;
    int kp = cb & 127;
    const float2* vb = (const float2*)(v + (size_t)b * L * H);
    float ax = 0.f, ay = 0.f;
    #pragma unroll 8
    for (int m = 0; m < ROWSC; m++) {
        int l = kp + m * CPB;
        float2 x = vb[(size_t)l * (H / 2) + tid];
        ax += x.x; ay += x.y;
    }
    ((float2*)(ws_f + OFF_PART + ((size_t)kp * B + b) * H))[tid] =
        make_float2(ax, ay);
}

// Grid = exactly 1024 blocks x 512 threads (4 blocks/CU -> fully resident,
// no second scheduling wave). Blocks 0..15 do sparse attention AND then the
// last 16 colsum slices; blocks 16..1023 do colsum slices 0..1007.
__global__ __launch_bounds__(512)
void mega_kernel(const float* __restrict__ q, const float* __restrict__ k,
                 const float* __restrict__ v, const int* __restrict__ qidx_p,
                 float* __restrict__ ws_f) {
    int bid = blockIdx.x;
    int tid = threadIdx.x;

    if (bid >= 16) {
        colsum_slice(bid - 16, tid, v, ws_f);
        return;
    }

    // ---------------- fused sparse attention ----------------
    int set = bid >> 3;   // 0 = hilbert, 1 = cantor
    int b   = bid & 7;

    __shared__ float qs[H];
    __shared__ float sc[MAX_N];
    __shared__ float probs[MAX_N];
    __shared__ int   idx[MAX_N];
    __shared__ int   n_sh;
    __shared__ float sinv_sh;

    if (tid < H / 4)
        ((float4*)qs)[tid] = ((const float4*)(q + (size_t)b * H))[tid];

    if (set == 1) {
        // Cantor: closed-form per-lane walk of the 7-bit interval path.
        // Final positions are m/3^7; idx = m*8191/2187 is never within
        // 4.6e-4 of an integer -> truncation matches numpy; all distinct.
        if (tid < 129) {
            double l = (tid == 128) ? 1.0 : 0.0;
            if (tid < 128) {
                double gap = 1.0;
                #pragma unroll
                for (int bit = 6; bit >= 0; --bit) {
                    double third = gap / 3.0;
                    if ((tid >> bit) & 1) { l += third; gap -= third; }
                    else                  { gap = third; }
                }
            }
            idx[tid] = (int)(l * (double)(L - 1));
        }
        if (tid == 0) n_sh = 129;
    } else {
        // Hilbert: 49 candidates on wave 0, ballot-compact (order is
        // irrelevant: softmax+sum is permutation-invariant).
        if (tid < 64) {
            int center = qidx_p[0];
            if (center > 9999) center = 9999;
            if (center < 0) center = 0;
            int cx, cy;
            d2xy_dev(128, center, &cx, &cy);
            int val = -1;
            if (tid < 49) {
                int x = cx + tid / 7 - 3, y = cy + tid % 7 - 3;
                if (x >= 0 && x < 128 && y >= 0 && y < 128) {
                    int i = xy2d_dev(128, x, y);
                    if (i < L) val = i;
                }
            }
            unsigned long long ball = __ballot(val >= 0);
            int pos = __popcll(ball & ((1ull << tid) - 1));
            if (val >= 0) idx[pos] = val;
            if (tid == 0) n_sh = __popcll(ball);
        }
    }
    __syncthreads();
    int n = n_sh;

    // scores: wave per key (8 waves)
    int wid = tid >> 6, lane = tid & 63;
    for (int j = wid; j < n; j += 8) {
        const float4* k4 =
            (const float4*)(k + ((size_t)b * L + (size_t)idx[j]) * H);
        float p = 0.f;
        #pragma unroll
        for (int i = 0; i < H / 256; i++) {
            float4 a = ((float4*)qs)[lane + i * 64];
            float4 c = k4[lane + i * 64];
            p += a.x * c.x + a.y * c.y + a.z * c.z + a.w * c.w;
        }
        #pragma unroll
        for (int off = 32; off; off >>= 1) p += __shfl_down(p, off);
        if (lane == 0) sc[j] = p * SCALE;
    }
    __syncthreads();

    // softmax on wave 0
    if (wid == 0) {
        float m = -1e30f;
        for (int j = lane; j < n; j += 64) m = fmaxf(m, sc[j]);
        #pragma unroll
        for (int mask = 32; mask; mask >>= 1) m = fmaxf(m, __shfl_xor(m, mask));
        float s = 0.f;
        for (int j = lane; j < n; j += 64) {
            float e = expf(sc[j] - m);
            probs[j] = e;
            s += e;
        }
        #pragma unroll
        for (int mask = 32; mask; mask >>= 1) s += __shfl_xor(s, mask);
        if (lane == 0) sinv_sh = 1.f / s;
    }
    __syncthreads();

    // PV: thread owns float2 column pair (2*tid, 2*tid+1)
    float ax = 0.f, ay = 0.f;
    #pragma unroll 8
    for (int j = 0; j < n; j++) {
        float p = probs[j];
        const float2 x =
            *(const float2*)(v + ((size_t)b * L + (size_t)idx[j]) * H + 2 * tid);
        ax += p * x.x; ay += p * x.y;
    }
    float sinv = sinv_sh;
    ((float2*)(ws_f + OFF_OUTS + ((size_t)set * B + b) * H))[tid] =
        make_float2(ax * sinv, ay * sinv);

    // ---- pick up one leftover colsum slice (keeps grid at exactly 1024) ----
    colsum_slice(NSLICE - 16 + bid, tid, v, ws_f);
}

// grid (B,4) x 256 threads: z-chunk of 64 float4 columns; 4 partial-groups
// of 32 summed per thread, LDS-reduced in fixed order -> deterministic.
__global__ __launch_bounds__(256)
void combine_kernel(const float* __restrict__ pw, const float* __restrict__ ws_f,
                    float* __restrict__ out) {
    int b    = blockIdx.x;
    int z    = blockIdx.y;
    int t    = threadIdx.x;
    int lane = t & 63;
    int psub = t >> 6;          // 0..3
    int c4   = z * 64 + lane;   // float4 column

    float4 s = make_float4(0.f, 0.f, 0.f, 0.f);
    #pragma unroll 8
    for (int i = 0; i < NPART / 4; i++) {
        int p = psub * (NPART / 4) + i;
        float4 x = ((const float4*)(ws_f + OFF_PART +
                                    ((size_t)p * B + b) * H))[c4];
        s.x += x.x; s.y += x.y; s.z += x.z; s.w += x.w;
    }

    __shared__ float4 red[4][64];
    red[psub][lane] = s;
    __syncthreads();
    if (psub == 0) {
        float4 a0 = red[0][lane], a1 = red[1][lane],
               a2 = red[2][lane], a3 = red[3][lane];
        float4 sm = make_float4(a0.x + a1.x + a2.x + a3.x,
                                a0.y + a1.y + a2.y + a3.y,
                                a0.z + a1.z + a2.z + a3.z,
                                a0.w + a1.w + a2.w + a3.w);

        float w0 = pw[0], w1 = pw[1], w2 = pw[2];
        float m  = fmaxf(w0, fmaxf(w1, w2));
        float e0 = expf(w0 - m), e1 = expf(w1 - m), e2 = expf(w2 - m);
        float invs = 1.f / (e0 + e1 + e2);

        float4 hil = ((const float4*)(ws_f + OFF_OUTS + (size_t)b * H))[c4];
        float4 can = ((const float4*)(ws_f + OFF_OUTS + ((size_t)B + b) * H))[c4];
        const float il = 1.0f / (float)L;  // dragon weights exactly 0 -> uniform
        float4 o;
        o.x = (e0 * hil.x + e1 * can.x + e2 * (sm.x * il)) * invs;
        o.y = (e0 * hil.y + e1 * can.y + e2 * (sm.y * il)) * invs;
        o.z = (e0 * hil.z + e1 * can.z + e2 * (sm.z * il)) * invs;
        o.w = (e0 * hil.w + e1 * can.w + e2 * (sm.w * il)) * invs;
        ((float4*)(out + (size_t)b * H))[c4] = o;
    }
}

extern "C" void kernel_launch(void* const* d_in, const int* in_sizes, int n_in,
                              void* d_out, int out_size, void* d_ws, size_t ws_size,
                              hipStream_t stream) {
    const float* q  = (const float*)d_in[0];
    const float* k  = (const float*)d_in[1];
    const float* v  = (const float*)d_in[2];
    const float* pw = (const float*)d_in[3];
    const int* qidx = (const int*)d_in[4];

    float* ws_f = (float*)d_ws;

    mega_kernel<<<NSLICE, 512, 0, stream>>>(q, k, v, qidx, ws_f);
    combine_kernel<<<dim3(B, 4), 256, 0, stream>>>(pw, ws_f, (float*)d_out);
}

// Round 12
// 60.649 us; speedup vs baseline: 1.0278x; 1.0278x over previous
//
#include <hip/hip_runtime.h>
#include <math.h>

#define B 8
#define L 8192
#define H 1024
#define SCALE 0.03125f   // 1/sqrt(1024)

#define MAX_N 160        // >= 129 cantor keys
#define CPBC  126        // colsum slices per batch (1008 blocks total)
#define ROWS_PER 65      // rows per colsum slice: 126*65 = 8190; rows 8190/8191
                         // are copied by the batch's two sparse blocks.
#define NPART 128        // partial rows per batch (126 colsum + 2 leftover)

// ws layout (float offsets) — total (2*B*H + NPART*B*H)*4 = 4.26 MB (safe).
//   OFF_OUTS: hil_out (B*H) then can_out (B*H)
//   OFF_PART: partials (NPART*B*H), layout [p][b][h]
#define OFF_OUTS 0
#define OFF_PART (2 * B * H)

__device__ inline void d2xy_dev(int n, int d, int* px, int* py) {
    int x = 0, y = 0;
    for (int s = 1; s < n; s *= 2) {
        int rx = 1 & (d / 2);
        int ry = 1 & (d ^ rx);
        if (ry == 0) {
            if (rx == 1) { x = s - 1 - x; y = s - 1 - y; }
            int t = x; x = y; y = t;
        }
        x += s * rx; y += s * ry;
        d /= 4;
    }
    *px = x; *py = y;
}

__device__ inline int xy2d_dev(int n, int x, int y) {
    int d = 0;
    for (int s = n / 2; s > 0; s /= 2) {
        int rx = ((x & s) > 0) ? 1 : 0;
        int ry = ((y & s) > 0) ? 1 : 0;
        d += s * s * ((3 * rx) ^ ry);
        if (ry == 0) {
            if (rx == 1) { x = s - 1 - x; y = s - 1 - y; }
            int t = x; x = y; y = t;
        }
    }
    return d;
}

// Grid = exactly 1024 blocks x 512 threads = 4 blocks/CU x 256 CU: the whole
// grid is resident in one scheduling round (no overflow tail).
// Blocks 0..15: sparse attention + copy of one leftover v-row.
// Blocks 16..1023: colsum slice (b = cb/126, j = cb%126), windowed row
// interleave l = j + m*126 -> a batch's 126 slices sweep one contiguous
// ~504KB window (8 linear streams machine-wide).
__global__ __launch_bounds__(512)
void mega_kernel(const float* __restrict__ q, const float* __restrict__ k,
                 const float* __restrict__ v, const int* __restrict__ qidx_p,
                 float* __restrict__ ws_f) {
    int bid = blockIdx.x;
    int tid = threadIdx.x;

    if (bid >= 16) {
        int cb = bid - 16;
        int b  = cb / CPBC;
        int j  = cb - b * CPBC;
        const float2* vb = (const float2*)(v + (size_t)b * L * H);
        float ax = 0.f, ay = 0.f;
        #pragma unroll 5
        for (int m = 0; m < ROWS_PER; m++) {
            int l = j + m * CPBC;
            float2 x = vb[(size_t)l * (H / 2) + tid];
            ax += x.x; ay += x.y;
        }
        ((float2*)(ws_f + OFF_PART + ((size_t)j * B + b) * H))[tid] =
            make_float2(ax, ay);
        return;
    }

    // ---------------- fused sparse attention ----------------
    int set = bid >> 3;   // 0 = hilbert, 1 = cantor
    int b   = bid & 7;

    __shared__ float qs[H];
    __shared__ float sc[MAX_N];
    __shared__ float probs[MAX_N];
    __shared__ int   idx[MAX_N];
    __shared__ int   n_sh;
    __shared__ float sinv_sh;

    if (tid < H / 4)
        ((float4*)qs)[tid] = ((const float4*)(q + (size_t)b * H))[tid];

    if (set == 1) {
        // Cantor: closed-form per-lane walk of the 7-bit interval path.
        // Final positions are m/3^7; idx = m*8191/2187 is never within
        // 4.6e-4 of an integer -> truncation matches numpy; all distinct.
        if (tid < 129) {
            double l = (tid == 128) ? 1.0 : 0.0;
            if (tid < 128) {
                double gap = 1.0;
                #pragma unroll
                for (int bit = 6; bit >= 0; --bit) {
                    double third = gap / 3.0;
                    if ((tid >> bit) & 1) { l += third; gap -= third; }
                    else                  { gap = third; }
                }
            }
            idx[tid] = (int)(l * (double)(L - 1));
        }
        if (tid == 0) n_sh = 129;
    } else {
        // Hilbert: 49 candidates on wave 0, ballot-compact (order is
        // irrelevant: softmax+sum is permutation-invariant).
        if (tid < 64) {
            int center = qidx_p[0];
            if (center > 9999) center = 9999;
            if (center < 0) center = 0;
            int cx, cy;
            d2xy_dev(128, center, &cx, &cy);
            int val = -1;
            if (tid < 49) {
                int x = cx + tid / 7 - 3, y = cy + tid % 7 - 3;
                if (x >= 0 && x < 128 && y >= 0 && y < 128) {
                    int i = xy2d_dev(128, x, y);
                    if (i < L) val = i;
                }
            }
            unsigned long long ball = __ballot(val >= 0);
            int pos = __popcll(ball & ((1ull << tid) - 1));
            if (val >= 0) idx[pos] = val;
            if (tid == 0) n_sh = __popcll(ball);
        }
    }
    __syncthreads();
    int n = n_sh;

    // scores: wave per key (8 waves)
    int wid = tid >> 6, lane = tid & 63;
    for (int j = wid; j < n; j += 8) {
        const float4* k4 =
            (const float4*)(k + ((size_t)b * L + (size_t)idx[j]) * H);
        float p = 0.f;
        #pragma unroll
        for (int i = 0; i < H / 256; i++) {
            float4 a = ((float4*)qs)[lane + i * 64];
            float4 c = k4[lane + i * 64];
            p += a.x * c.x + a.y * c.y + a.z * c.z + a.w * c.w;
        }
        #pragma unroll
        for (int off = 32; off; off >>= 1) p += __shfl_down(p, off);
        if (lane == 0) sc[j] = p * SCALE;
    }
    __syncthreads();

    // softmax on wave 0
    if (wid == 0) {
        float m = -1e30f;
        for (int j = lane; j < n; j += 64) m = fmaxf(m, sc[j]);
        #pragma unroll
        for (int mask = 32; mask; mask >>= 1) m = fmaxf(m, __shfl_xor(m, mask));
        float s = 0.f;
        for (int j = lane; j < n; j += 64) {
            float e = expf(sc[j] - m);
            probs[j] = e;
            s += e;
        }
        #pragma unroll
        for (int mask = 32; mask; mask >>= 1) s += __shfl_xor(s, mask);
        if (lane == 0) sinv_sh = 1.f / s;
    }
    __syncthreads();

    // PV: thread owns float2 column pair (2*tid, 2*tid+1)
    float ax = 0.f, ay = 0.f;
    #pragma unroll 8
    for (int j = 0; j < n; j++) {
        float p = probs[j];
        const float2 x =
            *(const float2*)(v + ((size_t)b * L + (size_t)idx[j]) * H + 2 * tid);
        ax += p * x.x; ay += p * x.y;
    }
    float sinv = sinv_sh;
    ((float2*)(ws_f + OFF_OUTS + ((size_t)set * B + b) * H))[tid] =
        make_float2(ax * sinv, ay * sinv);

    // ---- leftover colsum row (4KB copy): row 8190+set -> partial 126+set ----
    {
        const float2* vrow =
            (const float2*)(v + ((size_t)b * L + (size_t)(L - 2 + set)) * H);
        ((float2*)(ws_f + OFF_PART + ((size_t)(CPBC + set) * B + b) * H))[tid] =
            vrow[tid];
    }
}

// grid (B,4) x 256 threads: z-chunk of 64 float4 columns; 4 partial-groups
// of 32 summed per thread, LDS-reduced in fixed order -> deterministic.
__global__ __launch_bounds__(256)
void combine_kernel(const float* __restrict__ pw, const float* __restrict__ ws_f,
                    float* __restrict__ out) {
    int b    = blockIdx.x;
    int z    = blockIdx.y;
    int t    = threadIdx.x;
    int lane = t & 63;
    int psub = t >> 6;          // 0..3
    int c4   = z * 64 + lane;   // float4 column

    float4 s = make_float4(0.f, 0.f, 0.f, 0.f);
    #pragma unroll 8
    for (int i = 0; i < NPART / 4; i++) {
        int p = psub * (NPART / 4) + i;
        float4 x = ((const float4*)(ws_f + OFF_PART +
                                    ((size_t)p * B + b) * H))[c4];
        s.x += x.x; s.y += x.y; s.z += x.z; s.w += x.w;
    }

    __shared__ float4 red[4][64];
    red[psub][lane] = s;
    __syncthreads();
    if (psub == 0) {
        float4 a0 = red[0][lane], a1 = red[1][lane],
               a2 = red[2][lane], a3 = red[3][lane];
        float4 sm = make_float4(a0.x + a1.x + a2.x + a3.x,
                                a0.y + a1.y + a2.y + a3.y,
                                a0.z + a1.z + a2.z + a3.z,
                                a0.w + a1.w + a2.w + a3.w);

        float w0 = pw[0], w1 = pw[1], w2 = pw[2];
        float m  = fmaxf(w0, fmaxf(w1, w2));
        float e0 = expf(w0 - m), e1 = expf(w1 - m), e2 = expf(w2 - m);
        float invs = 1.f / (e0 + e1 + e2);

        float4 hil = ((const float4*)(ws_f + OFF_OUTS + (size_t)b * H))[c4];
        float4 can = ((const float4*)(ws_f + OFF_OUTS + ((size_t)B + b) * H))[c4];
        const float il = 1.0f / (float)L;  // dragon weights exactly 0 -> uniform
        float4 o;
        o.x = (e0 * hil.x + e1 * can.x + e2 * (sm.x * il)) * invs;
        o.y = (e0 * hil.y + e1 * can.y + e2 * (sm.y * il)) * invs;
        o.z = (e0 * hil.z + e1 * can.z + e2 * (sm.z * il)) * invs;
        o.w = (e0 * hil.w + e1 * can.w + e2 * (sm.w * il)) * invs;
        ((float4*)(out + (size_t)b * H))[c4] = o;
    }
}

extern "C" void kernel_launch(void* const* d_in, const int* in_sizes, int n_in,
                              void* d_out, int out_size, void* d_ws, size_t ws_size,
                              hipStream_t stream) {
    const float* q  = (const float*)d_in[0];
    const float* k  = (const float*)d_in[1];
    const float* v  = (const float*)d_in[2];
    const float* pw = (const float*)d_in[3];
    const int* qidx = (const int*)d_in[4];

    float* ws_f = (float*)d_ws;

    mega_kernel<<<16 + CPBC * B, 512, 0, stream>>>(q, k, v, qidx, ws_f);
    combine_kernel<<<dim3(B, 4), 256, 0, stream>>>(pw, ws_f, (float*)d_out);
}

// Round 13
// 58.307 us; speedup vs baseline: 1.0691x; 1.0402x over previous
//
#include <hip/hip_runtime.h>
#include <math.h>

#define B 8
#define L 8192
#define H 1024
#define SCALE 0.03125f   // 1/sqrt(1024)

#define MAX_N 160        // >= 129 cantor keys
#define CPB   128        // colsum slices per batch
#define NPART CPB        // partial rows per batch

// ws layout (float offsets) — total (2*B*H + NPART*B*H)*4 = 4.26 MB (safe).
//   OFF_OUTS: hil_out (B*H) then can_out (B*H)
//   OFF_PART: partials (NPART*B*H), layout [p][b][h]
#define OFF_OUTS 0
#define OFF_PART (2 * B * H)

__device__ inline void d2xy_dev(int n, int d, int* px, int* py) {
    int x = 0, y = 0;
    for (int s = 1; s < n; s *= 2) {
        int rx = 1 & (d / 2);
        int ry = 1 & (d ^ rx);
        if (ry == 0) {
            if (rx == 1) { x = s - 1 - x; y = s - 1 - y; }
            int t = x; x = y; y = t;
        }
        x += s * rx; y += s * ry;
        d /= 4;
    }
    *px = x; *py = y;
}

__device__ inline int xy2d_dev(int n, int x, int y) {
    int d = 0;
    for (int s = n / 2; s > 0; s /= 2) {
        int rx = ((x & s) > 0) ? 1 : 0;
        int ry = ((y & s) > 0) ? 1 : 0;
        d += s * s * ((3 * rx) ^ ry);
        if (ry == 0) {
            if (rx == 1) { x = s - 1 - x; y = s - 1 - y; }
            int t = x; x = y; y = t;
        }
    }
    return d;
}

// Blocks 0..15: fused sparse attention (set = bid>>3, b = bid&7).
// Blocks 16..1039: colsum slice (b = cb>>7, kp = cb&127).
// Colsum: 8KB-burst windowed interleave — chunk c = kp + m*128 covers rows
// 2c,2c+1 (512 thr x float4 = 8 KB contiguous per step); the 128 slices of a
// batch collectively sweep a 1 MB contiguous window per step (8 linear
// streams machine-wide). Thread halves pair-reduce via LDS -> one partial
// row per slice (NPART=128, footprint unchanged).
__global__ __launch_bounds__(512)
void mega_kernel(const float* __restrict__ q, const float* __restrict__ k,
                 const float* __restrict__ v, const int* __restrict__ qidx_p,
                 float* __restrict__ ws_f) {
    int bid = blockIdx.x;
    int tid = threadIdx.x;

    if (bid >= 16) {
        int cb = bid - 16;
        int b  = cb >> 7;
        int kp = cb & 127;
        int half = tid >> 8;     // 0: row 2c, 1: row 2c+1
        int col  = tid & 255;    // float4 column

        const float4* vb = (const float4*)(v + (size_t)b * L * H);
        float4 acc = make_float4(0.f, 0.f, 0.f, 0.f);
        #pragma unroll 8
        for (int m = 0; m < 32; m++) {
            int c = kp + m * 128;
            float4 x = vb[(size_t)(2 * c + half) * (H / 4) + col];
            acc.x += x.x; acc.y += x.y; acc.z += x.z; acc.w += x.w;
        }

        __shared__ float4 red[256];
        if (half) red[col] = acc;
        __syncthreads();
        if (!half) {
            float4 r = red[col];
            r.x += acc.x; r.y += acc.y; r.z += acc.z; r.w += acc.w;
            ((float4*)(ws_f + OFF_PART + ((size_t)kp * B + b) * H))[col] = r;
        }
        return;
    }

    // ---------------- fused sparse attention ----------------
    int set = bid >> 3;   // 0 = hilbert, 1 = cantor
    int b   = bid & 7;

    __shared__ float qs[H];
    __shared__ float sc[MAX_N];
    __shared__ float probs[MAX_N];
    __shared__ int   idx[MAX_N];
    __shared__ int   n_sh;
    __shared__ float sinv_sh;

    if (tid < H / 4)
        ((float4*)qs)[tid] = ((const float4*)(q + (size_t)b * H))[tid];

    if (set == 1) {
        // Cantor: closed-form per-lane walk of the 7-bit interval path.
        // Final positions are m/3^7; idx = m*8191/2187 is never within
        // 4.6e-4 of an integer -> truncation matches numpy; all distinct.
        if (tid < 129) {
            double l = (tid == 128) ? 1.0 : 0.0;
            if (tid < 128) {
                double gap = 1.0;
                #pragma unroll
                for (int bit = 6; bit >= 0; --bit) {
                    double third = gap / 3.0;
                    if ((tid >> bit) & 1) { l += third; gap -= third; }
                    else                  { gap = third; }
                }
            }
            idx[tid] = (int)(l * (double)(L - 1));
        }
        if (tid == 0) n_sh = 129;
    } else {
        // Hilbert: 49 candidates on wave 0, ballot-compact (order is
        // irrelevant: softmax+sum is permutation-invariant).
        if (tid < 64) {
            int center = qidx_p[0];
            if (center > 9999) center = 9999;
            if (center < 0) center = 0;
            int cx, cy;
            d2xy_dev(128, center, &cx, &cy);
            int val = -1;
            if (tid < 49) {
                int x = cx + tid / 7 - 3, y = cy + tid % 7 - 3;
                if (x >= 0 && x < 128 && y >= 0 && y < 128) {
                    int i = xy2d_dev(128, x, y);
                    if (i < L) val = i;
                }
            }
            unsigned long long ball = __ballot(val >= 0);
            int pos = __popcll(ball & ((1ull << tid) - 1));
            if (val >= 0) idx[pos] = val;
            if (tid == 0) n_sh = __popcll(ball);
        }
    }
    __syncthreads();
    int n = n_sh;

    // scores: wave per key (8 waves)
    int wid = tid >> 6, lane = tid & 63;
    for (int j = wid; j < n; j += 8) {
        const float4* k4 =
            (const float4*)(k + ((size_t)b * L + (size_t)idx[j]) * H);
        float p = 0.f;
        #pragma unroll
        for (int i = 0; i < H / 256; i++) {
            float4 a = ((float4*)qs)[lane + i * 64];
            float4 c = k4[lane + i * 64];
            p += a.x * c.x + a.y * c.y + a.z * c.z + a.w * c.w;
        }
        #pragma unroll
        for (int off = 32; off; off >>= 1) p += __shfl_down(p, off);
        if (lane == 0) sc[j] = p * SCALE;
    }
    __syncthreads();

    // softmax on wave 0
    if (wid == 0) {
        float m = -1e30f;
        for (int j = lane; j < n; j += 64) m = fmaxf(m, sc[j]);
        #pragma unroll
        for (int mask = 32; mask; mask >>= 1) m = fmaxf(m, __shfl_xor(m, mask));
        float s = 0.f;
        for (int j = lane; j < n; j += 64) {
            float e = expf(sc[j] - m);
            probs[j] = e;
            s += e;
        }
        #pragma unroll
        for (int mask = 32; mask; mask >>= 1) s += __shfl_xor(s, mask);
        if (lane == 0) sinv_sh = 1.f / s;
    }
    __syncthreads();

    // PV: thread owns float2 column pair (2*tid, 2*tid+1)
    float ax = 0.f, ay = 0.f;
    #pragma unroll 8
    for (int j = 0; j < n; j++) {
        float p = probs[j];
        const float2 x =
            *(const float2*)(v + ((size_t)b * L + (size_t)idx[j]) * H + 2 * tid);
        ax += p * x.x; ay += p * x.y;
    }
    float sinv = sinv_sh;
    ((float2*)(ws_f + OFF_OUTS + ((size_t)set * B + b) * H))[tid] =
        make_float2(ax * sinv, ay * sinv);
}

// grid (B,4) x 256 threads: z-chunk of 64 float4 columns; 4 partial-groups
// of 32 summed per thread, LDS-reduced in fixed order -> deterministic.
__global__ __launch_bounds__(256)
void combine_kernel(const float* __restrict__ pw, const float* __restrict__ ws_f,
                    float* __restrict__ out) {
    int b    = blockIdx.x;
    int z    = blockIdx.y;
    int t    = threadIdx.x;
    int lane = t & 63;
    int psub = t >> 6;          // 0..3
    int c4   = z * 64 + lane;   // float4 column

    float4 s = make_float4(0.f, 0.f, 0.f, 0.f);
    #pragma unroll 8
    for (int i = 0; i < NPART / 4; i++) {
        int p = psub * (NPART / 4) + i;
        float4 x = ((const float4*)(ws_f + OFF_PART +
                                    ((size_t)p * B + b) * H))[c4];
        s.x += x.x; s.y += x.y; s.z += x.z; s.w += x.w;
    }

    __shared__ float4 red[4][64];
    red[psub][lane] = s;
    __syncthreads();
    if (psub == 0) {
        float4 a0 = red[0][lane], a1 = red[1][lane],
               a2 = red[2][lane], a3 = red[3][lane];
        float4 sm = make_float4(a0.x + a1.x + a2.x + a3.x,
                                a0.y + a1.y + a2.y + a3.y,
                                a0.z + a1.z + a2.z + a3.z,
                                a0.w + a1.w + a2.w + a3.w);

        float w0 = pw[0], w1 = pw[1], w2 = pw[2];
        float m  = fmaxf(w0, fmaxf(w1, w2));
        float e0 = expf(w0 - m), e1 = expf(w1 - m), e2 = expf(w2 - m);
        float invs = 1.f / (e0 + e1 + e2);

        float4 hil = ((const float4*)(ws_f + OFF_OUTS + (size_t)b * H))[c4];
        float4 can = ((const float4*)(ws_f + OFF_OUTS + ((size_t)B + b) * H))[c4];
        const float il = 1.0f / (float)L;  // dragon weights exactly 0 -> uniform
        float4 o;
        o.x = (e0 * hil.x + e1 * can.x + e2 * (sm.x * il)) * invs;
        o.y = (e0 * hil.y + e1 * can.y + e2 * (sm.y * il)) * invs;
        o.z = (e0 * hil.z + e1 * can.z + e2 * (sm.z * il)) * invs;
        o.w = (e0 * hil.w + e1 * can.w + e2 * (sm.w * il)) * invs;
        ((float4*)(out + (size_t)b * H))[c4] = o;
    }
}

extern "C" void kernel_launch(void* const* d_in, const int* in_sizes, int n_in,
                              void* d_out, int out_size, void* d_ws, size_t ws_size,
                              hipStream_t stream) {
    const float* q  = (const float*)d_in[0];
    const float* k  = (const float*)d_in[1];
    const float* v  = (const float*)d_in[2];
    const float* pw = (const float*)d_in[3];
    const int* qidx = (const int*)d_in[4];

    float* ws_f = (float*)d_ws;

    mega_kernel<<<16 + CPB * B, 512, 0, stream>>>(q, k, v, qidx, ws_f);
    combine_kernel<<<dim3(B, 4), 256, 0, stream>>>(pw, ws_f, (float*)d_out);
}